// Round 1
// 677.593 us; speedup vs baseline: 1.0486x; 1.0486x over previous
//
#include <hip/hip_runtime.h>
#include <math.h>

#define BB 4096
#define DD 1024
#define TT 50
#define NKS 13108      // ceil(131072/10)
#define NPOS 16
#define NW_TOTAL (BB + NKS)

// ---------------------------------------------------------------------------
// Kernel 1 (fused): pack every label row (b-side AND strided k-side) into
// three 50-bit masks: p0 = pure (1,0), p1 = pure (0,1), dd = double (1,1).
// One wave per row; lane t handles label slot t; __ballot builds the bitset.
// ---------------------------------------------------------------------------
__global__ __launch_bounds__(256) void label_codes_all(const int* __restrict__ xl,
                                                       const int* __restrict__ ql,
                                                       unsigned long long* __restrict__ bmask,
                                                       unsigned long long* __restrict__ kmask) {
    int w    = (blockIdx.x * blockDim.x + threadIdx.x) >> 6;
    int lane = threadIdx.x & 63;
    if (w >= NW_TOTAL) return;
    const int2* p;
    unsigned long long* o;
    if (w < BB) {                       // b-side row, stride T*L = 100 ints
        p = (const int2*)(xl + (size_t)w * (TT * 2));
        o = bmask + (size_t)w * 3;
    } else {                            // k-side strided row, stride 1000 ints
        int kk = w - BB;
        p = (const int2*)(ql + (size_t)kk * (TT * 2 * 10));
        o = kmask + (size_t)kk * 3;
    }
    int l0 = 0, l1 = 0;
    if (lane < TT) { int2 ll = p[lane]; l0 = ll.x; l1 = ll.y; }
    bool a = (lane < TT);
    unsigned long long p0 = __ballot(a && l0 && !l1);
    unsigned long long p1 = __ballot(a && l1 && !l0);
    unsigned long long dd = __ballot(a && l0 && l1);
    if (lane == 0) { o[0] = p0; o[1] = p1; o[2] = dd; }
}

__device__ inline float d4(float4 a, float4 b) {
    return a.x * b.x + a.y * b.y + a.z * b.z + a.w * b.w;
}

// ---------------------------------------------------------------------------
// Kernel 2 (fused scan + loss), one block per b.
// Phase A: ordered scan over k chunks of 256; mask iff
//   popc(ss)*1 + popc(dd)*s + popc(mix)*v >= 25   (== mean over T >= 0.5)
// Collect first 16 masked k (in k order) into LDS, early exit.
// Single barrier per chunk via double-buffered per-wave counts.
// Phase B: wave wid handles j = wid, wid+4, ... ; dot + ||k||^2 in one pass,
// 6x shfl_xor wave reduce (no barriers), softplus(-2*cos) on lane 0.
// ---------------------------------------------------------------------------
__global__ __launch_bounds__(256) void scan_loss(const unsigned long long* __restrict__ bmask,
                                                 const unsigned long long* __restrict__ kmask,
                                                 const float* __restrict__ x_q,
                                                 const float* __restrict__ qf,
                                                 float* __restrict__ per_b) {
    int b    = blockIdx.x;
    int tid  = threadIdx.x;
    int lane = tid & 63, wid = tid >> 6;

    unsigned long long pA0 = bmask[(size_t)b * 3 + 0];
    unsigned long long pA1 = bmask[(size_t)b * 3 + 1];
    unsigned long long dA  = bmask[(size_t)b * 3 + 2];
    unsigned long long sA  = pA0 | pA1;

    const float v = 1.0f / (sqrtf(2.0f) + 1e-8f);   // mixed (1,1)x(1,0) dot
    const float s = v * v + v * v;                  // (1,1)x(1,1) dot

    __shared__ int   wcnt[2][4];
    __shared__ int   slist[NPOS];
    __shared__ float red[4];
    unsigned long long lmask = (1ull << lane) - 1ull;

    int found = 0;
    int ph = 0;
    for (int base = 0; base < NKS; base += 256) {
        int kk = base + tid;
        bool m = false;
        if (kk < NKS) {
            unsigned long long pK0 = kmask[(size_t)kk * 3 + 0];
            unsigned long long pK1 = kmask[(size_t)kk * 3 + 1];
            unsigned long long dK  = kmask[(size_t)kk * 3 + 2];
            unsigned long long sK  = pK0 | pK1;
            unsigned long long mss = (pA0 & pK0) | (pA1 & pK1);
            unsigned long long mdd = dA & dK;
            unsigned long long mix = (dA & sK) | (sA & dK);
            float sum = (float)__popcll(mss) + (float)__popcll(mdd) * s + (float)__popcll(mix) * v;
            m = (sum >= 25.0f);
        }
        unsigned long long bal = __ballot(m);
        if (lane == 0) wcnt[ph][wid] = __popcll(bal);
        __syncthreads();
        int w0 = wcnt[ph][0], w1 = wcnt[ph][1], w2 = wcnt[ph][2], w3 = wcnt[ph][3];
        int woff = (wid > 0 ? w0 : 0) + (wid > 1 ? w1 : 0) + (wid > 2 ? w2 : 0);
        if (m) {
            int pos = found + woff + __popcll(bal & lmask);
            if (pos < NPOS) slist[pos] = kk;
        }
        found += w0 + w1 + w2 + w3;
        ph ^= 1;                 // next chunk writes the other buffer: 1 barrier/chunk
        if (found >= NPOS) break;
    }
    int count = found < NPOS ? found : NPOS;
    __syncthreads();             // slist visible to all waves

    // --- Phase B: loss. Each wave holds the full x_q row (16 floats/lane). ---
    const float4* xr = (const float4*)(x_q + (size_t)b * DD);
    float4 xq0 = xr[lane], xq1 = xr[lane + 64], xq2 = xr[lane + 128], xq3 = xr[lane + 192];
    float nn = d4(xq0, xq0) + d4(xq1, xq1) + d4(xq2, xq2) + d4(xq3, xq3);
    for (int o = 32; o > 0; o >>= 1) nn += __shfl_xor(nn, o);
    float nq = sqrtf(nn) + 1e-8f;

    float part = 0.0f;
    for (int j = wid; j < count; j += 4) {
        int kk = slist[j];
        const float4* rv = (const float4*)(qf + (size_t)kk * 10 * DD);
        float4 r0 = rv[lane], r1 = rv[lane + 64], r2 = rv[lane + 128], r3 = rv[lane + 192];
        float dotp = d4(xq0, r0) + d4(xq1, r1) + d4(xq2, r2) + d4(xq3, r3);
        float nk   = d4(r0, r0) + d4(r1, r1) + d4(r2, r2) + d4(r3, r3);
        for (int o = 32; o > 0; o >>= 1) {
            dotp += __shfl_xor(dotp, o);
            nk   += __shfl_xor(nk, o);
        }
        if (lane == 0) {
            float denom = nq * (sqrtf(nk) + 1e-8f);
            float sims = (dotp / denom) * 2.0f;     // / TEMPERATURE(0.5)
            float z = -sims;                        // loss = softplus(-sims)
            part += fmaxf(z, 0.0f) + log1pf(expf(-fabsf(z)));
        }
    }
    if (lane == 0) red[wid] = part;
    __syncthreads();
    if (tid == 0) {
        float pa = red[0] + red[1] + red[2] + red[3];
        per_b[b] = (count > 0) ? pa / (float)count : 0.0f;
    }
}

// ---------------------------------------------------------------------------
// Kernel 3: single-block tree reduction of the 4096 per-b partials -> mean.
// (Kept separate: single-address atomics measured ~600us for 4096 adds in R1.)
// ---------------------------------------------------------------------------
__global__ __launch_bounds__(256) void final_reduce(const float* __restrict__ per_b,
                                                    float* __restrict__ out) {
    int tid = threadIdx.x;
    float s = 0.0f;
    for (int i = tid; i < BB; i += 256) s += per_b[i];
    for (int o = 32; o > 0; o >>= 1) s += __shfl_down(s, o);
    __shared__ float red[4];
    int lane = tid & 63, wid = tid >> 6;
    if (lane == 0) red[wid] = s;
    __syncthreads();
    if (tid == 0) out[0] = (red[0] + red[1] + red[2] + red[3]) * (1.0f / (float)BB);
}

extern "C" void kernel_launch(void* const* d_in, const int* in_sizes, int n_in,
                              void* d_out, int out_size, void* d_ws, size_t ws_size,
                              hipStream_t stream) {
    const float* x_q            = (const float*)d_in[0];
    const int*   x_label        = (const int*)d_in[1];
    const float* queue_features = (const float*)d_in[2];
    const int*   queue_labels   = (const int*)d_in[3];
    float* out = (float*)d_out;

    unsigned long long* bmask = (unsigned long long*)d_ws;     // B*3 u64
    unsigned long long* kmask = bmask + (size_t)BB * 3;        // NKS*3 u64
    float* per_b = (float*)(kmask + (size_t)NKS * 3);          // B float

    // one wave per label row: 4096 b-rows + 13108 strided k-rows
    label_codes_all<<<(NW_TOTAL * 64 + 255) / 256, 256, 0, stream>>>(
        x_label, queue_labels, bmask, kmask);

    scan_loss<<<BB, 256, 0, stream>>>(bmask, kmask, x_q, queue_features, per_b);

    final_reduce<<<1, 256, 0, stream>>>(per_b, out);
}